// Round 6
// baseline (185.037 us; speedup 1.0000x reference)
//
#include <hip/hip_runtime.h>

typedef short bf16x8 __attribute__((ext_vector_type(8)));
typedef float f32x4 __attribute__((ext_vector_type(4)));
typedef unsigned long long u64x2 __attribute__((ext_vector_type(2)));
typedef unsigned short u16;

// ---------- helpers ----------

__device__ __forceinline__ u16 f2b(float f) {
  unsigned int u = __float_as_uint(f);
  u += 0x7fffu + ((u >> 16) & 1u);   // RNE
  return (u16)(u >> 16);
}
__device__ __forceinline__ float b2f(u16 h) {
  return __uint_as_float((unsigned int)h << 16);
}

__device__ __forceinline__ void gload16(const void* g, void* l) {
  __builtin_amdgcn_global_load_lds(
      (const __attribute__((address_space(1))) void*)g,
      (__attribute__((address_space(3))) void*)l, 16, 0, 0);
}

#define SBAR() __builtin_amdgcn_sched_barrier(0)
#define BAR()  do { SBAR(); __builtin_amdgcn_s_barrier(); SBAR(); } while (0)

// ---------- 128x128 BK=32 4-wave NT GEMM, 2-deep prefetch (3 buffers) ------
// A: rows [i0,i0+128) x K row-major lda; B: rows [j0,j0+128) x K row-major ldb.
// D[m][n] = sum_k A[i0+m][k]*B[j0+n][k], k in [0, nk*32).
// 256 thr = 4 waves (2M x 2N); per-wave C 64x64 = acc[4][4].
// LDS 48 KiB: 3 bufs x (A 128x32 + B 128x32) bf16.
// Swizzle: 16B slot ^= (row>>1)&3 (2-way = free); applied on the GLOBAL source
// col (linear gload_lds dest, rule 21) and on the ds_read byte offset.
// Pipeline: tile kt's 4 loads are issued 2 iterations before use; steady-state
// wait is vmcnt(8) (2 tiles in flight) -> ~2 compute phases of latency cover.

__device__ __forceinline__ void stage32(
    const u16* __restrict__ gA, int lda, const u16* __restrict__ gB, int ldb,
    u16* bufA, u16* bufB)
{
  const int t = threadIdx.x;
  const int r0 = t >> 2;                            // row 0..63 (+64 chunk 2)
  const int cs = (((t & 3) ^ ((r0 >> 1) & 3)) * 8); // inverse-swizzled src col
  char* da = (char*)bufA + t * 16;
  char* db = (char*)bufB + t * 16;
  gload16(gA + (size_t)r0 * lda + cs, da);
  gload16(gA + (size_t)(r0 + 64) * lda + cs, da + 4096);
  gload16(gB + (size_t)r0 * ldb + cs, db);
  gload16(gB + (size_t)(r0 + 64) * ldb + cs, db + 4096);
}

__device__ __forceinline__ void gemm128(
    const u16* __restrict__ A, int lda, const u16* __restrict__ B, int ldb,
    int i0, int j0, int nk, u16* lds, f32x4 acc[4][4])
{
  const int t = threadIdx.x, lane = t & 63, wid = t >> 6;
  const int wrow = wid >> 1, wcol = wid & 1;
  const int rr = lane & 15, kg = lane >> 4;
  const int off = ((kg ^ ((rr >> 1) & 3)) << 4);   // swizzled byte slot
  const u16* Ab = A + (size_t)i0 * lda;
  const u16* Bb = B + (size_t)j0 * ldb;

  u16 *cA = lds,         *cB = lds + 4096;    // compute buffer (tile kt)
  u16 *nA = lds + 8192,  *nB = lds + 12288;   // next (tile kt+1)
  u16 *sA = lds + 16384, *sB = lds + 20480;   // stage target (tile kt+2)

  stage32(Ab, lda, Bb, ldb, cA, cB);
  if (nk > 1) stage32(Ab + 32, lda, Bb + 32, ldb, nA, nB);

  for (int kt = 0; kt < nk; ++kt) {
    if (kt + 2 < nk) {
      stage32(Ab + (size_t)(kt + 2) * 32, lda,
              Bb + (size_t)(kt + 2) * 32, ldb, sA, sB);
      asm volatile("s_waitcnt vmcnt(8)" ::: "memory");   // tile kt landed
    } else if (kt + 1 < nk) {
      asm volatile("s_waitcnt vmcnt(4)" ::: "memory");
    } else {
      asm volatile("s_waitcnt vmcnt(0)" ::: "memory");
    }
    BAR();                                     // publish tile kt (all waves)
    bf16x8 af[4], bf[4];
#pragma unroll
    for (int mi = 0; mi < 4; ++mi)
      af[mi] = *(const bf16x8*)((const char*)cA + (wrow * 64 + mi * 16 + rr) * 64 + off);
#pragma unroll
    for (int ni = 0; ni < 4; ++ni)
      bf[ni] = *(const bf16x8*)((const char*)cB + (wcol * 64 + ni * 16 + rr) * 64 + off);
    __builtin_amdgcn_s_setprio(1);
#pragma unroll
    for (int mi = 0; mi < 4; ++mi)
#pragma unroll
      for (int ni = 0; ni < 4; ++ni)
        acc[mi][ni] = __builtin_amdgcn_mfma_f32_16x16x32_bf16(
            af[mi], bf[ni], acc[mi][ni], 0, 0, 0);
    __builtin_amdgcn_s_setprio(0);
    BAR();                                     // reads of tile kt done
    u16* tA = cA; cA = nA; nA = sA; sA = tA;   // rotate buffers
    u16* tB = cB; cB = nB; nB = sB; sB = tB;
  }
}

// ---------- kernel 0: fp32 -> bf16 conversion (x, stacked W (+I on Wk), P) --
__global__ __launch_bounds__(256) void k_convert(
    const float* __restrict__ x, const float* __restrict__ Wq,
    const float* __restrict__ Wk, const float* __restrict__ Wv,
    const float* __restrict__ P,
    u16* __restrict__ xb, u16* __restrict__ Wb, u16* __restrict__ Ptab)
{
  const size_t NX = 8388608, NW = 3145728;
  size_t base = ((size_t)blockIdx.x * 256 + threadIdx.x) * 4;
  if (base < NX) {
    float4 v = *(const float4*)(x + base);
    u16* dst = xb + base;
    dst[0] = f2b(v.x); dst[1] = f2b(v.y); dst[2] = f2b(v.z); dst[3] = f2b(v.w);
  } else if (base < NX + NW) {
    size_t wb = base - NX;
    int sel = (int)(wb >> 20);
    const float* W = (sel == 0) ? Wq : ((sel == 1) ? Wk : Wv);
    size_t within = wb & 1048575;
    float4 v = *(const float4*)(W + within);
    if (sel == 1) {            // Wk + I  (folds the +x of pos into the GEMM)
      int row = (int)(within >> 10), c0 = (int)(within & 1023);
      if (row >= c0 && row < c0 + 4) ((float*)&v)[row - c0] += 1.0f;
    }
    u16* dst = Wb + wb;
    dst[0] = f2b(v.x); dst[1] = f2b(v.y); dst[2] = f2b(v.z); dst[3] = f2b(v.w);
  } else {
    size_t pi = base - NX - NW;
    float4 v = *(const float4*)(P + pi);
    u16* dst = Ptab + pi;
    dst[0] = f2b(v.x); dst[1] = f2b(v.y); dst[2] = f2b(v.z); dst[3] = f2b(v.w);
  }
}

// ---------- kernel 1: QKV projection ----------
// C[8192][3072] = xb @ Wb^T. bj 0-7 -> Q, 8-15 -> K' = k + x + P (x folded
// into Wk via +I; P added in epilogue from bf16 Ptab), 16-23 -> V^T.
__global__ __launch_bounds__(256, 3) void k_qkv(
    const u16* __restrict__ xb, const u16* __restrict__ Wb,
    const float* __restrict__ bq, const float* __restrict__ bk,
    const float* __restrict__ bv, const u16* __restrict__ Ptab,
    u16* __restrict__ Qb, u16* __restrict__ Kpb, u16* __restrict__ Vtb)
{
  __shared__ __align__(16) u16 lds[24576];
  const int bx = blockIdx.x;
  const int bi = bx & 63, bj = bx >> 6;   // 64 M-tiles x 24 N-tiles
  const int i0 = bi * 128, j0 = bj * 128;
  f32x4 acc[4][4];
#pragma unroll
  for (int a = 0; a < 4; ++a)
#pragma unroll
    for (int b = 0; b < 4; ++b) acc[a][b] = (f32x4){0.f, 0.f, 0.f, 0.f};

  gemm128(xb, 1024, Wb, 1024, i0, j0, 32, lds, acc);

  const int t = threadIdx.x, lane = t & 63, wid = t >> 6;
  const int wrow = wid >> 1, wcol = wid & 1;
  const int rr = lane & 15, kg = lane >> 4;
  const int sec = j0 >> 10;
  if (sec == 0) {
#pragma unroll
    for (int mi = 0; mi < 4; ++mi)
#pragma unroll
      for (int ni = 0; ni < 4; ++ni)
#pragma unroll
        for (int r = 0; r < 4; ++r) {
          int m = i0 + wrow * 64 + mi * 16 + kg * 4 + r;
          int n = j0 + wcol * 64 + ni * 16 + rr;
          int d = n & 1023;
          Qb[(size_t)m * 1024 + d] = f2b(acc[mi][ni][r] + bq[d]);
        }
  } else if (sec == 1) {
#pragma unroll
    for (int mi = 0; mi < 4; ++mi)
#pragma unroll
      for (int ni = 0; ni < 4; ++ni)
#pragma unroll
        for (int r = 0; r < 4; ++r) {
          int m = i0 + wrow * 64 + mi * 16 + kg * 4 + r;
          int n = j0 + wcol * 64 + ni * 16 + rr;
          int d = n & 1023;
          int s = m & 2047;
          float pv = b2f(Ptab[(size_t)s * 1024 + d]);
          Kpb[(size_t)m * 1024 + d] = f2b(acc[mi][ni][r] + bk[d] + pv);
        }
  } else {
    // V: transpose through swizzled LDS, then coalesced 16B stores
    u16* lt = lds;   // 128 x 128 bf16: lt[d_local][s_local ^ swz]
#pragma unroll
    for (int mi = 0; mi < 4; ++mi)
#pragma unroll
      for (int ni = 0; ni < 4; ++ni) {
        int cl = wcol * 64 + ni * 16 + rr;            // d_local
        float bvd = bv[(j0 & 1023) + cl];
#pragma unroll
        for (int r = 0; r < 4; ++r) {
          int rl = wrow * 64 + mi * 16 + kg * 4 + r;  // s_local
          lt[cl * 128 + (rl ^ ((cl & 7) << 3))] = f2b(acc[mi][ni][r] + bvd);
        }
      }
    __syncthreads();
    int b = i0 >> 11, s0 = i0 & 2047, d0 = j0 & 1023;
#pragma unroll
    for (int rnd = 0; rnd < 8; ++rnd) {
      int c = rnd * 256 + t;                  // 2048 x 16B chunks
      int drow = c >> 4, c16 = c & 15;
      int src = drow * 128 + ((c16 * 8) ^ ((drow & 7) << 3));
      *(u64x2*)(&Vtb[((size_t)b * 1024 + d0 + drow) * 2048 + s0 + c16 * 8]) =
          *(const u64x2*)(&lt[src]);
    }
  }
}

// ---------- kernel 2: scores -> exp (no-max softmax numerator) + rowsum ----
// Pb[b][i][j] = exp((Q.K')/32) (causal-masked), bf16, unnormalized.
// rowsum[b][i] += per-block partial row sums (global atomicAdd).
__global__ __launch_bounds__(256, 3) void k_scores(
    const u16* __restrict__ Qb, const u16* __restrict__ Kpb,
    u16* __restrict__ Pb, float* __restrict__ rowsum)
{
  __shared__ __align__(16) u16 lds[24576];
  const int bx = blockIdx.x;
  const int b = bx / 136;
  const int tt = bx - b * 136;
  int bi = 0;
  while ((bi + 1) * (bi + 2) / 2 <= tt) ++bi;
  const int bj = tt - bi * (bi + 1) / 2;
  const int i0 = bi * 128, j0 = bj * 128;
  const u16* A = Qb + (size_t)b * 2048 * 1024;
  const u16* B = Kpb + (size_t)b * 2048 * 1024;

  f32x4 acc[4][4];
#pragma unroll
  for (int a = 0; a < 4; ++a)
#pragma unroll
    for (int c = 0; c < 4; ++c) acc[a][c] = (f32x4){0.f, 0.f, 0.f, 0.f};

  gemm128(A, 1024, B, 1024, i0, j0, 32, lds, acc);

  const int t = threadIdx.x, lane = t & 63, wid = t >> 6;
  const int wrow = wid >> 1, wcol = wid & 1;
  const int rr = lane & 15, kg = lane >> 4;
  float* lrs = (float*)lds;                    // reuse LDS: 128 row partials
  __syncthreads();
  if (t < 128) lrs[t] = 0.f;
  __syncthreads();
  u16* Pbb = Pb + (size_t)b * 2048 * 2048;
  const bool diag = (bi == bj);
#pragma unroll
  for (int mi = 0; mi < 4; ++mi)
#pragma unroll
    for (int r = 0; r < 4; ++r) {
      int lm = wrow * 64 + mi * 16 + kg * 4 + r;
      int m = i0 + lm;
      float rs = 0.f;
#pragma unroll
      for (int ni = 0; ni < 4; ++ni) {
        int n = j0 + wcol * 64 + ni * 16 + rr;
        float e = __expf(acc[mi][ni][r] * 0.03125f);
        if (diag && n > m) e = 0.f;
        Pbb[(size_t)m * 2048 + n] = f2b(e);
        rs += e;
      }
      rs += __shfl_xor(rs, 1, 16);             // reduce over the 16 rr lanes
      rs += __shfl_xor(rs, 2, 16);
      rs += __shfl_xor(rs, 4, 16);
      rs += __shfl_xor(rs, 8, 16);
      if (rr == 0) atomicAdd(&lrs[lm], rs);
    }
  __syncthreads();
  if (t < 128) atomicAdd(&rowsum[((size_t)b << 11) + i0 + t], lrs[t]);
}

// ---------- kernel 3: out = (Pexp @ V) / rowsum (pre-transposed Vtb) ------
__global__ __launch_bounds__(256, 3) void k_pv(
    const u16* __restrict__ Pb, const u16* __restrict__ Vtb,
    const float* __restrict__ rowsum, float* __restrict__ out)
{
  __shared__ __align__(16) u16 lds[24576];
  const int bx = blockIdx.x;
  const int b = bx >> 7;
  const int bi = 15 - ((bx >> 3) & 15);   // big tiles first
  const int bj = bx & 7;
  const int i0 = bi * 128, j0 = bj * 128;
  const u16* A = Pb + (size_t)b * 2048 * 2048;   // lda 2048
  const u16* B = Vtb + (size_t)b * 1024 * 2048;  // ldb 2048

  f32x4 acc[4][4];
#pragma unroll
  for (int a = 0; a < 4; ++a)
#pragma unroll
    for (int c = 0; c < 4; ++c) acc[a][c] = (f32x4){0.f, 0.f, 0.f, 0.f};

  // causal: P zero for j >= (bi+1)*128 -> only (bi+1)*4 K-steps of 32
  gemm128(A, 2048, B, 2048, i0, j0, (bi + 1) * 4, lds, acc);

  const int t = threadIdx.x, lane = t & 63, wid = t >> 6;
  const int wrow = wid >> 1, wcol = wid & 1;
  const int rr = lane & 15, kg = lane >> 4;
  const float* rsb = rowsum + ((size_t)b << 11);
  float* ob = out + (size_t)b * 2048 * 1024;
#pragma unroll
  for (int mi = 0; mi < 4; ++mi)
#pragma unroll
    for (int r = 0; r < 4; ++r) {
      int m = i0 + wrow * 64 + mi * 16 + kg * 4 + r;
      float inv = 1.0f / rsb[m];
#pragma unroll
      for (int ni = 0; ni < 4; ++ni) {
        int n = j0 + wcol * 64 + ni * 16 + rr;
        ob[(size_t)m * 1024 + n] = acc[mi][ni][r] * inv;
      }
    }
}

// ---------- launch ----------
extern "C" void kernel_launch(void* const* d_in, const int* in_sizes, int n_in,
                              void* d_out, int out_size, void* d_ws, size_t ws_size,
                              hipStream_t stream) {
  const float* x  = (const float*)d_in[0];
  const float* Wq = (const float*)d_in[1];
  const float* bq = (const float*)d_in[2];
  const float* Wk = (const float*)d_in[3];
  const float* bk = (const float*)d_in[4];
  const float* Wv = (const float*)d_in[5];
  const float* bv = (const float*)d_in[6];
  const float* P  = (const float*)d_in[7];
  float* out = (float*)d_out;

  char* w = (char*)d_ws;
  u16*   xb     = (u16*)(w);                   // 16 MB
  u16*   Wb     = (u16*)(w + (16ull << 20));   //  6 MB
  u16*   Qb     = (u16*)(w + (22ull << 20));   // 16 MB
  u16*   Kpb    = (u16*)(w + (38ull << 20));   // 16 MB
  u16*   Vtb    = (u16*)(w + (54ull << 20));   // 16 MB
  u16*   Pb     = (u16*)(w + (70ull << 20));   // 32 MB
  u16*   Ptab   = (u16*)(w + (102ull << 20));  //  4 MB
  float* rowsum = (float*)(w + (106ull << 20));// 32 KB

  hipLaunchKernelGGL(k_convert, dim3(13312), dim3(256), 0, stream,
                     x, Wq, Wk, Wv, P, xb, Wb, Ptab);
  hipMemsetAsync(rowsum, 0, 8192 * sizeof(float), stream);
  hipLaunchKernelGGL(k_qkv, dim3(1536), dim3(256), 0, stream,
                     xb, Wb, bq, bk, bv, Ptab, Qb, Kpb, Vtb);
  hipLaunchKernelGGL(k_scores, dim3(544), dim3(256), 0, stream,
                     Qb, Kpb, Pb, rowsum);
  hipLaunchKernelGGL(k_pv, dim3(512), dim3(256), 0, stream,
                     Pb, Vtb, rowsum, out);
}

// Round 7
// 184.491 us; speedup vs baseline: 1.0030x; 1.0030x over previous
//
#include <hip/hip_runtime.h>

typedef short bf16x8 __attribute__((ext_vector_type(8)));
typedef float f32x4 __attribute__((ext_vector_type(4)));
typedef unsigned long long u64x2 __attribute__((ext_vector_type(2)));
typedef unsigned short u16;

// ---------- helpers ----------

__device__ __forceinline__ u16 f2b(float f) {
  unsigned int u = __float_as_uint(f);
  u += 0x7fffu + ((u >> 16) & 1u);   // RNE
  return (u16)(u >> 16);
}
__device__ __forceinline__ float b2f(u16 h) {
  return __uint_as_float((unsigned int)h << 16);
}

__device__ __forceinline__ void gload16(const void* g, void* l) {
  __builtin_amdgcn_global_load_lds(
      (const __attribute__((address_space(1))) void*)g,
      (__attribute__((address_space(3))) void*)l, 16, 0, 0);
}

#define SBAR() __builtin_amdgcn_sched_barrier(0)
#define BAR()  do { SBAR(); __builtin_amdgcn_s_barrier(); SBAR(); } while (0)
#define VM0()  do { asm volatile("s_waitcnt vmcnt(0)" ::: "memory"); SBAR(); } while (0)

// ============ 256x256 8-wave NT GEMM, 8-phase / 4-slot ring pipeline =======
// A: rows [i0,i0+256) x K row-major lda; B: rows [j0,j0+256) x K row-major ldb.
// D[m][n] = sum_k A[i0+m][k]*B[j0+n][k], k in [0, nkt*32). nkt even, >= 4.
// 512 thr = 8 waves (2M x 4N); per-wave C = 128x64 = acc[8][4].
// LDS 128 KiB = 4 slots x (A 256x32 + B 256x32). Slot s = kt & 3; staging
// runs 3 sub-tiles ahead; vmcnt(6) once per sub-tile (= instrs issued after
// B(kt+1): A(kt+2)+B(kt+2)+A(kt+3) = 3x2). Swizzle: 16B col-slot ^= (row>>1)&3
// -> every bank-quad served by exactly 8 lanes per ds_read_b128 (optimum).

__device__ __forceinline__ void stage_kt(const u16* g, int ld, u16* dst) {
  const int t = threadIdx.x;
#pragma unroll
  for (int r = 0; r < 2; ++r) {
    int idx = r * 512 + t;
    int row = idx >> 2, sl = idx & 3;
    gload16(g + (size_t)row * ld + ((sl ^ ((row >> 1) & 3)) << 3),
            (char*)dst + idx * 16);
  }
}

// read 4 frags at rows base+mi*16 (base = warp-row-base + rr), col-slot kg
__device__ __forceinline__ void rd4(const u16* slot, int base, int kg, bf16x8 a[4]) {
  const int cs = ((kg ^ ((base >> 1) & 3)) << 3);
#pragma unroll
  for (int mi = 0; mi < 4; ++mi)
    a[mi] = *(const bf16x8*)(slot + (base + mi * 16) * 32 + cs);
}

__device__ __forceinline__ void mm16(const bf16x8 a[4], const bf16x8 b[4],
                                     f32x4 acc[8][4], int rh) {
  __builtin_amdgcn_s_setprio(1);
#pragma unroll
  for (int mi = 0; mi < 4; ++mi)
#pragma unroll
    for (int ni = 0; ni < 4; ++ni)
      acc[rh * 4 + mi][ni] = __builtin_amdgcn_mfma_f32_16x16x32_bf16(
          a[mi], b[ni], acc[rh * 4 + mi][ni], 0, 0, 0);
  __builtin_amdgcn_s_setprio(0);
}

__device__ __forceinline__ void ktbody(
    int kt, int L, const u16* As, int lda, const u16* Bs, int ldb,
    u16* lds, int aBase0, int aBase1, int bBase, int kg,
    bf16x8 aC0[4], bf16x8 bCur[4], bf16x8 bNxt[4], f32x4 acc[8][4])
{
  const u16* slot = lds + (kt & 3) * 16384;
  bf16x8 aC1[4];
  // ---- phase A: read A(rh1) of kt; stage A(kt+3); vmcnt; MFMA rh0 ----
  rd4(slot, aBase1, kg, aC1);
  if (kt + 3 <= L)
    stage_kt(As + (size_t)(kt + 3) * 32, lda, lds + ((kt + 3) & 3) * 16384);
  if (kt + 3 <= L)      { asm volatile("s_waitcnt vmcnt(6)" ::: "memory"); }
  else if (kt + 2 <= L) { asm volatile("s_waitcnt vmcnt(4)" ::: "memory"); }
  else                  { asm volatile("s_waitcnt vmcnt(0)" ::: "memory"); }
  SBAR();
  BAR();
  mm16(aC0, bCur, acc, 0);
  BAR();
  // ---- phase B: read A(rh0)+B of kt+1; stage B(kt+3); MFMA rh1 ----
  if (kt < L) {
    const u16* sn = lds + ((kt + 1) & 3) * 16384;
    rd4(sn, aBase0, kg, aC0);
    rd4(sn + 8192, bBase, kg, bNxt);
  }
  if (kt + 3 <= L)
    stage_kt(Bs + (size_t)(kt + 3) * 32, ldb,
             lds + ((kt + 3) & 3) * 16384 + 8192);
  BAR();
  mm16(aC1, bCur, acc, 1);
  BAR();
}

__device__ __forceinline__ void gemm256(
    const u16* __restrict__ A, int lda, const u16* __restrict__ B, int ldb,
    int i0, int j0, int nkt, u16* lds, f32x4 acc[8][4])
{
  const int t = threadIdx.x, lane = t & 63, wid = t >> 6;
  const int wr = wid >> 2, wc = wid & 3;
  const int rr = lane & 15, kg = lane >> 4;
  const u16* As = A + (size_t)i0 * lda;
  const u16* Bs = B + (size_t)j0 * ldb;
  const int aBase0 = wr * 128 + rr;
  const int aBase1 = wr * 128 + 64 + rr;
  const int bBase  = wc * 64 + rr;
  const int L = nkt - 1;

  // prologue: stage sub-tiles 0,1,2 (12 instrs); first slot landed at vmcnt(8)
#pragma unroll
  for (int k = 0; k < 3; ++k) {
    u16* sl = lds + k * 16384;
    stage_kt(As + (size_t)k * 32, lda, sl);
    stage_kt(Bs + (size_t)k * 32, ldb, sl + 8192);
  }
  asm volatile("s_waitcnt vmcnt(8)" ::: "memory");
  SBAR();
  BAR();
  bf16x8 aC0[4], bA[4], bB[4];
  rd4(lds, aBase0, kg, aC0);
  rd4(lds + 8192, bBase, kg, bA);

  for (int kt = 0; kt < nkt; kt += 2) {
    ktbody(kt,     L, As, lda, Bs, ldb, lds, aBase0, aBase1, bBase, kg, aC0, bA, bB, acc);
    ktbody(kt + 1, L, As, lda, Bs, ldb, lds, aBase0, aBase1, bBase, kg, aC0, bB, bA, acc);
  }
  VM0();   // drain any residual staging before LDS reuse
  BAR();
}

// ============ 128x128 BK=32 4-wave NT GEMM (r5-proven, for k_pv) ===========
__device__ __forceinline__ void stage32(
    const u16* __restrict__ gA, int lda, const u16* __restrict__ gB, int ldb,
    u16* bufA, u16* bufB)
{
  const int t = threadIdx.x;
  const int r0 = t >> 2;
  const int cs = (((t & 3) ^ ((r0 >> 1) & 3)) * 8);
  char* da = (char*)bufA + t * 16;
  char* db = (char*)bufB + t * 16;
  gload16(gA + (size_t)r0 * lda + cs, da);
  gload16(gA + (size_t)(r0 + 64) * lda + cs, da + 4096);
  gload16(gB + (size_t)r0 * ldb + cs, db);
  gload16(gB + (size_t)(r0 + 64) * ldb + cs, db + 4096);
}

__device__ __forceinline__ void gemm128(
    const u16* __restrict__ A, int lda, const u16* __restrict__ B, int ldb,
    int i0, int j0, int nk, u16* lds, f32x4 acc[4][4])
{
  u16* bA0 = lds;
  u16* bB0 = lds + 4096;
  u16* bA1 = lds + 8192;
  u16* bB1 = lds + 12288;
  const int t = threadIdx.x, lane = t & 63, wid = t >> 6;
  const int wrow = wid >> 1, wcol = wid & 1;
  const int rr = lane & 15, kg = lane >> 4;
  const int off = ((kg ^ ((rr >> 1) & 3)) << 4);
  const u16* Ab = A + (size_t)i0 * lda;
  const u16* Bb = B + (size_t)j0 * ldb;

  stage32(Ab, lda, Bb, ldb, bA0, bB0);
  for (int kt = 0; kt < nk; ++kt) {
    if (kt + 1 < nk) {
      stage32(Ab + (size_t)(kt + 1) * 32, lda, Bb + (size_t)(kt + 1) * 32, ldb,
              (kt & 1) ? bA0 : bA1, (kt & 1) ? bB0 : bB1);
      asm volatile("s_waitcnt vmcnt(4)" ::: "memory");
    } else {
      asm volatile("s_waitcnt vmcnt(0)" ::: "memory");
    }
    BAR();
    const u16* cA = (kt & 1) ? bA1 : bA0;
    const u16* cB = (kt & 1) ? bB1 : bB0;
    bf16x8 af[4], bf[4];
#pragma unroll
    for (int mi = 0; mi < 4; ++mi)
      af[mi] = *(const bf16x8*)((const char*)cA + (wrow * 64 + mi * 16 + rr) * 64 + off);
#pragma unroll
    for (int ni = 0; ni < 4; ++ni)
      bf[ni] = *(const bf16x8*)((const char*)cB + (wcol * 64 + ni * 16 + rr) * 64 + off);
    __builtin_amdgcn_s_setprio(1);
#pragma unroll
    for (int mi = 0; mi < 4; ++mi)
#pragma unroll
      for (int ni = 0; ni < 4; ++ni)
        acc[mi][ni] = __builtin_amdgcn_mfma_f32_16x16x32_bf16(
            af[mi], bf[ni], acc[mi][ni], 0, 0, 0);
    __builtin_amdgcn_s_setprio(0);
    BAR();
  }
}

// ---------- kernel 0: fp32 -> bf16 conversion (x, stacked W (+I on Wk), P) --
__global__ __launch_bounds__(256) void k_convert(
    const float* __restrict__ x, const float* __restrict__ Wq,
    const float* __restrict__ Wk, const float* __restrict__ Wv,
    const float* __restrict__ P,
    u16* __restrict__ xb, u16* __restrict__ Wb, u16* __restrict__ Ptab)
{
  const size_t NX = 8388608, NW = 3145728;
  size_t base = ((size_t)blockIdx.x * 256 + threadIdx.x) * 4;
  if (base < NX) {
    float4 v = *(const float4*)(x + base);
    u16* dst = xb + base;
    dst[0] = f2b(v.x); dst[1] = f2b(v.y); dst[2] = f2b(v.z); dst[3] = f2b(v.w);
  } else if (base < NX + NW) {
    size_t wb = base - NX;
    int sel = (int)(wb >> 20);
    const float* W = (sel == 0) ? Wq : ((sel == 1) ? Wk : Wv);
    size_t within = wb & 1048575;
    float4 v = *(const float4*)(W + within);
    if (sel == 1) {            // Wk + I  (folds the +x of pos into the GEMM)
      int row = (int)(within >> 10), c0 = (int)(within & 1023);
      if (row >= c0 && row < c0 + 4) ((float*)&v)[row - c0] += 1.0f;
    }
    u16* dst = Wb + wb;
    dst[0] = f2b(v.x); dst[1] = f2b(v.y); dst[2] = f2b(v.z); dst[3] = f2b(v.w);
  } else {
    size_t pi = base - NX - NW;
    float4 v = *(const float4*)(P + pi);
    u16* dst = Ptab + pi;
    dst[0] = f2b(v.x); dst[1] = f2b(v.y); dst[2] = f2b(v.z); dst[3] = f2b(v.w);
  }
}

// ---------- kernel 1: QKV projection (256x256 8-phase) ----------
// C[8192][3072] = xb @ Wb^T. bj 0-3 -> Q, 4-7 -> K' = k + x + P, 8-11 -> V^T.
__global__ __launch_bounds__(512, 2) void k_qkv(
    const u16* __restrict__ xb, const u16* __restrict__ Wb,
    const float* __restrict__ bq, const float* __restrict__ bk,
    const float* __restrict__ bv, const u16* __restrict__ Ptab,
    u16* __restrict__ Qb, u16* __restrict__ Kpb, u16* __restrict__ Vtb)
{
  extern __shared__ __align__(16) u16 lds[];
  const int bx = blockIdx.x;
  const int bi = bx & 31, bj = bx >> 5;   // 32 M-tiles x 12 N-tiles
  const int i0 = bi * 256, j0 = bj * 256;
  f32x4 acc[8][4];
#pragma unroll
  for (int a = 0; a < 8; ++a)
#pragma unroll
    for (int b = 0; b < 4; ++b) acc[a][b] = (f32x4){0.f, 0.f, 0.f, 0.f};

  gemm256(xb, 1024, Wb, 1024, i0, j0, 32, lds, acc);

  const int t = threadIdx.x, lane = t & 63, wid = t >> 6;
  const int wrow = wid >> 2, wcol = wid & 3;
  const int rr = lane & 15, kg = lane >> 4;
  const int sec = j0 >> 10;
  if (sec == 0) {
#pragma unroll
    for (int mi = 0; mi < 8; ++mi)
#pragma unroll
      for (int ni = 0; ni < 4; ++ni)
#pragma unroll
        for (int r = 0; r < 4; ++r) {
          int m = i0 + wrow * 128 + mi * 16 + kg * 4 + r;
          int n = j0 + wcol * 64 + ni * 16 + rr;
          int d = n & 1023;
          Qb[(size_t)m * 1024 + d] = f2b(acc[mi][ni][r] + bq[d]);
        }
  } else if (sec == 1) {
#pragma unroll
    for (int mi = 0; mi < 8; ++mi)
#pragma unroll
      for (int ni = 0; ni < 4; ++ni)
#pragma unroll
        for (int r = 0; r < 4; ++r) {
          int m = i0 + wrow * 128 + mi * 16 + kg * 4 + r;
          int n = j0 + wcol * 64 + ni * 16 + rr;
          int d = n & 1023;
          int s = m & 2047;
          float pv = b2f(Ptab[(size_t)s * 1024 + d]);
          Kpb[(size_t)m * 1024 + d] = f2b(acc[mi][ni][r] + bk[d] + pv);
        }
  } else {
    // V: transpose through swizzled LDS (256x256), then coalesced 16B stores
    u16* lt = lds;
#pragma unroll
    for (int mi = 0; mi < 8; ++mi)
#pragma unroll
      for (int ni = 0; ni < 4; ++ni) {
        int cl = wcol * 64 + ni * 16 + rr;            // d_local
        float bvd = bv[(j0 & 1023) + cl];
#pragma unroll
        for (int r = 0; r < 4; ++r) {
          int rl = wrow * 128 + mi * 16 + kg * 4 + r; // s_local
          lt[cl * 256 + (rl ^ ((cl & 7) << 3))] = f2b(acc[mi][ni][r] + bvd);
        }
      }
    __syncthreads();
    int b = i0 >> 11, s0 = i0 & 2047, d0 = j0 & 1023;
#pragma unroll
    for (int rnd = 0; rnd < 16; ++rnd) {
      int c = rnd * 512 + t;                  // 8192 x 16B chunks
      int drow = c >> 5, c16 = c & 31;
      int src = drow * 256 + ((c16 * 8) ^ ((drow & 7) << 3));
      *(u64x2*)(&Vtb[((size_t)b * 1024 + d0 + drow) * 2048 + s0 + c16 * 8]) =
          *(const u64x2*)(&lt[src]);
    }
  }
}

// ---------- kernel 2: scores -> exp numerator + rowsum (256x256 8-phase) ---
__global__ __launch_bounds__(512, 2) void k_scores(
    const u16* __restrict__ Qb, const u16* __restrict__ Kpb,
    u16* __restrict__ Pb, float* __restrict__ rowsum)
{
  extern __shared__ __align__(16) u16 lds[];
  const int bx = blockIdx.x;
  const int b = bx / 36;
  const int tt = bx - b * 36;
  int bi = 0;
  while ((bi + 1) * (bi + 2) / 2 <= tt) ++bi;
  const int bj = tt - bi * (bi + 1) / 2;
  const int i0 = bi * 256, j0 = bj * 256;
  const u16* A = Qb + (size_t)b * 2048 * 1024;
  const u16* B = Kpb + (size_t)b * 2048 * 1024;

  f32x4 acc[8][4];
#pragma unroll
  for (int a = 0; a < 8; ++a)
#pragma unroll
    for (int c = 0; c < 4; ++c) acc[a][c] = (f32x4){0.f, 0.f, 0.f, 0.f};

  gemm256(A, 1024, B, 1024, i0, j0, 32, lds, acc);

  const int t = threadIdx.x, lane = t & 63, wid = t >> 6;
  const int wrow = wid >> 2, wcol = wid & 3;
  const int rr = lane & 15, kg = lane >> 4;
  float* lrs = (float*)lds;                    // 256 row partials
  __syncthreads();
  if (t < 256) lrs[t] = 0.f;
  __syncthreads();
  u16* Pbb = Pb + (size_t)b * 2048 * 2048;
  const bool diag = (bi == bj);
#pragma unroll
  for (int mi = 0; mi < 8; ++mi)
#pragma unroll
    for (int r = 0; r < 4; ++r) {
      int lm = wrow * 128 + mi * 16 + kg * 4 + r;
      int m = i0 + lm;
      float rs = 0.f;
#pragma unroll
      for (int ni = 0; ni < 4; ++ni) {
        int n = j0 + wcol * 64 + ni * 16 + rr;
        float e = __expf(acc[mi][ni][r] * 0.03125f);
        if (diag && n > m) e = 0.f;
        Pbb[(size_t)m * 2048 + n] = f2b(e);
        rs += e;
      }
      rs += __shfl_xor(rs, 1, 16);
      rs += __shfl_xor(rs, 2, 16);
      rs += __shfl_xor(rs, 4, 16);
      rs += __shfl_xor(rs, 8, 16);
      if (rr == 0) atomicAdd(&lrs[lm], rs);
    }
  __syncthreads();
  if (t < 256) atomicAdd(&rowsum[((size_t)b << 11) + i0 + t], lrs[t]);
}

// ---------- kernel 3: out = (Pexp @ V) / rowsum (128x128 template) ---------
__global__ __launch_bounds__(256, 4) void k_pv(
    const u16* __restrict__ Pb, const u16* __restrict__ Vtb,
    const float* __restrict__ rowsum, float* __restrict__ out)
{
  __shared__ __align__(16) u16 lds[16384];
  const int bx = blockIdx.x;
  const int b = bx >> 7;
  const int bi = 15 - ((bx >> 3) & 15);   // big tiles first
  const int bj = bx & 7;
  const int i0 = bi * 128, j0 = bj * 128;
  const u16* A = Pb + (size_t)b * 2048 * 2048;   // lda 2048
  const u16* B = Vtb + (size_t)b * 1024 * 2048;  // ldb 2048

  f32x4 acc[4][4];
#pragma unroll
  for (int a = 0; a < 4; ++a)
#pragma unroll
    for (int c = 0; c < 4; ++c) acc[a][c] = (f32x4){0.f, 0.f, 0.f, 0.f};

  gemm128(A, 2048, B, 2048, i0, j0, (bi + 1) * 4, lds, acc);

  const int t = threadIdx.x, lane = t & 63, wid = t >> 6;
  const int wrow = wid >> 1, wcol = wid & 1;
  const int rr = lane & 15, kg = lane >> 4;
  const float* rsb = rowsum + ((size_t)b << 11);
  float* ob = out + (size_t)b * 2048 * 1024;
#pragma unroll
  for (int mi = 0; mi < 4; ++mi)
#pragma unroll
    for (int r = 0; r < 4; ++r) {
      int m = i0 + wrow * 64 + mi * 16 + kg * 4 + r;
      float inv = 1.0f / rsb[m];
#pragma unroll
      for (int ni = 0; ni < 4; ++ni) {
        int n = j0 + wcol * 64 + ni * 16 + rr;
        ob[(size_t)m * 1024 + n] = acc[mi][ni][r] * inv;
      }
    }
}

// ---------- launch ----------
extern "C" void kernel_launch(void* const* d_in, const int* in_sizes, int n_in,
                              void* d_out, int out_size, void* d_ws, size_t ws_size,
                              hipStream_t stream) {
  const float* x  = (const float*)d_in[0];
  const float* Wq = (const float*)d_in[1];
  const float* bq = (const float*)d_in[2];
  const float* Wk = (const float*)d_in[3];
  const float* bk = (const float*)d_in[4];
  const float* Wv = (const float*)d_in[5];
  const float* bv = (const float*)d_in[6];
  const float* P  = (const float*)d_in[7];
  float* out = (float*)d_out;

  char* w = (char*)d_ws;
  u16*   xb     = (u16*)(w);                   // 16 MB
  u16*   Wb     = (u16*)(w + (16ull << 20));   //  6 MB
  u16*   Qb     = (u16*)(w + (22ull << 20));   // 16 MB
  u16*   Kpb    = (u16*)(w + (38ull << 20));   // 16 MB
  u16*   Vtb    = (u16*)(w + (54ull << 20));   // 16 MB
  u16*   Pb     = (u16*)(w + (70ull << 20));   // 32 MB
  u16*   Ptab   = (u16*)(w + (102ull << 20));  //  4 MB
  float* rowsum = (float*)(w + (106ull << 20));// 32 KB

  const int LDSB = 131072;
  (void)hipFuncSetAttribute((const void*)k_qkv,
        hipFuncAttributeMaxDynamicSharedMemorySize, LDSB);
  (void)hipFuncSetAttribute((const void*)k_scores,
        hipFuncAttributeMaxDynamicSharedMemorySize, LDSB);

  hipLaunchKernelGGL(k_convert, dim3(13312), dim3(256), 0, stream,
                     x, Wq, Wk, Wv, P, xb, Wb, Ptab);
  hipMemsetAsync(rowsum, 0, 8192 * sizeof(float), stream);
  hipLaunchKernelGGL(k_qkv, dim3(384), dim3(512), LDSB, stream,
                     xb, Wb, bq, bk, bv, Ptab, Qb, Kpb, Vtb);
  hipLaunchKernelGGL(k_scores, dim3(144), dim3(512), LDSB, stream,
                     Qb, Kpb, Pb, rowsum);
  hipLaunchKernelGGL(k_pv, dim3(512), dim3(256), 0, stream,
                     Pb, Vtb, rowsum, out);
}

// Round 8
// 163.775 us; speedup vs baseline: 1.1298x; 1.1265x over previous
//
#include <hip/hip_runtime.h>

typedef short bf16x8 __attribute__((ext_vector_type(8)));
typedef float f32x4 __attribute__((ext_vector_type(4)));
typedef unsigned long long u64x2 __attribute__((ext_vector_type(2)));
typedef unsigned short u16;

// ---------- helpers ----------

__device__ __forceinline__ u16 f2b(float f) {
  unsigned int u = __float_as_uint(f);
  u += 0x7fffu + ((u >> 16) & 1u);   // RNE
  return (u16)(u >> 16);
}
__device__ __forceinline__ float b2f(u16 h) {
  return __uint_as_float((unsigned int)h << 16);
}

__device__ __forceinline__ void gload16(const void* g, void* l) {
  __builtin_amdgcn_global_load_lds(
      (const __attribute__((address_space(1))) void*)g,
      (__attribute__((address_space(3))) void*)l, 16, 0, 0);
}

#define SBAR() __builtin_amdgcn_sched_barrier(0)
#define BAR()  do { SBAR(); __builtin_amdgcn_s_barrier(); SBAR(); } while (0)

// ---------- 128x128 BK=32 4-wave NT GEMM, double-buffered, counted vmcnt ----
// (r5-proven: 742 TF effective, bank-conflict-free 2-way swizzle, 4 blocks/CU)
// A: rows [i0,i0+128) x K row-major lda; B: rows [j0,j0+128) x K row-major ldb.
// D[m][n] = sum_k A[i0+m][k]*B[j0+n][k], k in [0, nk*32).
// 256 thr = 4 waves (2M x 2N); per-wave C 64x64 = acc[4][4]. LDS 32 KiB.

__device__ __forceinline__ void stage32(
    const u16* __restrict__ gA, int lda, const u16* __restrict__ gB, int ldb,
    u16* bufA, u16* bufB)
{
  const int t = threadIdx.x;
  const int r0 = t >> 2;                            // row 0..63 (+64 chunk 2)
  const int cs = (((t & 3) ^ ((r0 >> 1) & 3)) * 8); // inverse-swizzled src col
  char* da = (char*)bufA + t * 16;
  char* db = (char*)bufB + t * 16;
  gload16(gA + (size_t)r0 * lda + cs, da);
  gload16(gA + (size_t)(r0 + 64) * lda + cs, da + 4096);
  gload16(gB + (size_t)r0 * ldb + cs, db);
  gload16(gB + (size_t)(r0 + 64) * ldb + cs, db + 4096);
}

__device__ __forceinline__ void gemm128(
    const u16* __restrict__ A, int lda, const u16* __restrict__ B, int ldb,
    int i0, int j0, int nk, u16* lds, f32x4 acc[4][4])
{
  u16* bA0 = lds;
  u16* bB0 = lds + 4096;
  u16* bA1 = lds + 8192;
  u16* bB1 = lds + 12288;
  const int t = threadIdx.x, lane = t & 63, wid = t >> 6;
  const int wrow = wid >> 1, wcol = wid & 1;
  const int rr = lane & 15, kg = lane >> 4;
  const int off = ((kg ^ ((rr >> 1) & 3)) << 4);   // swizzled byte slot
  const u16* Ab = A + (size_t)i0 * lda;
  const u16* Bb = B + (size_t)j0 * ldb;

  stage32(Ab, lda, Bb, ldb, bA0, bB0);
  for (int kt = 0; kt < nk; ++kt) {
    if (kt + 1 < nk) {
      stage32(Ab + (size_t)(kt + 1) * 32, lda, Bb + (size_t)(kt + 1) * 32, ldb,
              (kt & 1) ? bA0 : bA1, (kt & 1) ? bB0 : bB1);
      asm volatile("s_waitcnt vmcnt(4)" ::: "memory");  // tile kt landed
    } else {
      asm volatile("s_waitcnt vmcnt(0)" ::: "memory");
    }
    BAR();                                     // publish buf[kt&1]
    const u16* cA = (kt & 1) ? bA1 : bA0;
    const u16* cB = (kt & 1) ? bB1 : bB0;
    bf16x8 af[4], bf[4];
#pragma unroll
    for (int mi = 0; mi < 4; ++mi)
      af[mi] = *(const bf16x8*)((const char*)cA + (wrow * 64 + mi * 16 + rr) * 64 + off);
#pragma unroll
    for (int ni = 0; ni < 4; ++ni)
      bf[ni] = *(const bf16x8*)((const char*)cB + (wcol * 64 + ni * 16 + rr) * 64 + off);
    __builtin_amdgcn_s_setprio(1);
#pragma unroll
    for (int mi = 0; mi < 4; ++mi)
#pragma unroll
      for (int ni = 0; ni < 4; ++ni)
        acc[mi][ni] = __builtin_amdgcn_mfma_f32_16x16x32_bf16(
            af[mi], bf[ni], acc[mi][ni], 0, 0, 0);
    __builtin_amdgcn_s_setprio(0);
    BAR();                                     // reads of buf[kt&1] done
  }
}

// ---------- kernel 0: fp32->bf16 convert (x, W stack (+I on Wk), P) + memset
__global__ __launch_bounds__(256) void k_convert(
    const float* __restrict__ x, const float* __restrict__ Wq,
    const float* __restrict__ Wk, const float* __restrict__ Wv,
    const float* __restrict__ P,
    u16* __restrict__ xb, u16* __restrict__ Wb, u16* __restrict__ Ptab,
    float* __restrict__ rowsum)
{
  const size_t NX = 8388608, NW = 3145728;
  if (blockIdx.x == 13312) {                 // tail block: zero rowsum (8192 f)
    float4 z = {0.f, 0.f, 0.f, 0.f};
    for (int i = threadIdx.x; i < 2048; i += 256)
      ((float4*)rowsum)[i] = z;
    return;
  }
  size_t base = ((size_t)blockIdx.x * 256 + threadIdx.x) * 4;
  if (base < NX) {
    float4 v = *(const float4*)(x + base);
    u16* dst = xb + base;
    dst[0] = f2b(v.x); dst[1] = f2b(v.y); dst[2] = f2b(v.z); dst[3] = f2b(v.w);
  } else if (base < NX + NW) {
    size_t wb = base - NX;
    int sel = (int)(wb >> 20);
    const float* W = (sel == 0) ? Wq : ((sel == 1) ? Wk : Wv);
    size_t within = wb & 1048575;
    float4 v = *(const float4*)(W + within);
    if (sel == 1) {            // Wk + I  (folds the +x of pos into the GEMM)
      int row = (int)(within >> 10), c0 = (int)(within & 1023);
      if (row >= c0 && row < c0 + 4) ((float*)&v)[row - c0] += 1.0f;
    }
    u16* dst = Wb + wb;
    dst[0] = f2b(v.x); dst[1] = f2b(v.y); dst[2] = f2b(v.z); dst[3] = f2b(v.w);
  } else {
    size_t pi = base - NX - NW;
    float4 v = *(const float4*)(P + pi);
    u16* dst = Ptab + pi;
    dst[0] = f2b(v.x); dst[1] = f2b(v.y); dst[2] = f2b(v.z); dst[3] = f2b(v.w);
  }
}

// ---------- kernel 1: QKV projection (128x128 tiles) ----------
// C[8192][3072] = xb @ Wb^T. bj 0-7 -> Q, 8-15 -> K' = k + x + P (x folded
// into Wk via +I; P added in epilogue from bf16 Ptab), 16-23 -> V^T.
__global__ __launch_bounds__(256, 4) void k_qkv(
    const u16* __restrict__ xb, const u16* __restrict__ Wb,
    const float* __restrict__ bq, const float* __restrict__ bk,
    const float* __restrict__ bv, const u16* __restrict__ Ptab,
    u16* __restrict__ Qb, u16* __restrict__ Kpb, u16* __restrict__ Vtb)
{
  __shared__ __align__(16) u16 lds[16384];
  const int bx = blockIdx.x;
  const int bi = bx & 63, bj = bx >> 6;   // 64 M-tiles x 24 N-tiles
  const int i0 = bi * 128, j0 = bj * 128;
  f32x4 acc[4][4];
#pragma unroll
  for (int a = 0; a < 4; ++a)
#pragma unroll
    for (int b = 0; b < 4; ++b) acc[a][b] = (f32x4){0.f, 0.f, 0.f, 0.f};

  gemm128(xb, 1024, Wb, 1024, i0, j0, 32, lds, acc);

  const int t = threadIdx.x, lane = t & 63, wid = t >> 6;
  const int wrow = wid >> 1, wcol = wid & 1;
  const int rr = lane & 15, kg = lane >> 4;
  const int sec = j0 >> 10;
  if (sec == 0) {
#pragma unroll
    for (int mi = 0; mi < 4; ++mi)
#pragma unroll
      for (int ni = 0; ni < 4; ++ni)
#pragma unroll
        for (int r = 0; r < 4; ++r) {
          int m = i0 + wrow * 64 + mi * 16 + kg * 4 + r;
          int n = j0 + wcol * 64 + ni * 16 + rr;
          int d = n & 1023;
          Qb[(size_t)m * 1024 + d] = f2b(acc[mi][ni][r] + bq[d]);
        }
  } else if (sec == 1) {
#pragma unroll
    for (int mi = 0; mi < 4; ++mi)
#pragma unroll
      for (int ni = 0; ni < 4; ++ni)
#pragma unroll
        for (int r = 0; r < 4; ++r) {
          int m = i0 + wrow * 64 + mi * 16 + kg * 4 + r;
          int n = j0 + wcol * 64 + ni * 16 + rr;
          int d = n & 1023;
          int s = m & 2047;
          float pv = b2f(Ptab[(size_t)s * 1024 + d]);
          Kpb[(size_t)m * 1024 + d] = f2b(acc[mi][ni][r] + bk[d] + pv);
        }
  } else {
    // V: transpose through swizzled LDS, then coalesced 16B stores
    u16* lt = lds;   // 128 x 128 bf16: lt[d_local][s_local ^ swz]
#pragma unroll
    for (int mi = 0; mi < 4; ++mi)
#pragma unroll
      for (int ni = 0; ni < 4; ++ni) {
        int cl = wcol * 64 + ni * 16 + rr;            // d_local
        float bvd = bv[(j0 & 1023) + cl];
#pragma unroll
        for (int r = 0; r < 4; ++r) {
          int rl = wrow * 64 + mi * 16 + kg * 4 + r;  // s_local
          lt[cl * 128 + (rl ^ ((cl & 7) << 3))] = f2b(acc[mi][ni][r] + bvd);
        }
      }
    __syncthreads();
    int b = i0 >> 11, s0 = i0 & 2047, d0 = j0 & 1023;
#pragma unroll
    for (int rnd = 0; rnd < 8; ++rnd) {
      int c = rnd * 256 + t;                  // 2048 x 16B chunks
      int drow = c >> 4, c16 = c & 15;
      int src = drow * 128 + ((c16 * 8) ^ ((drow & 7) << 3));
      *(u64x2*)(&Vtb[((size_t)b * 1024 + d0 + drow) * 2048 + s0 + c16 * 8]) =
          *(const u64x2*)(&lt[src]);
    }
  }
}

// ---------- kernel 2: scores -> exp (no-max softmax numerator) + rowsum ----
// Pb[b][i][j] = exp((Q.K')/32) (causal-masked), bf16, unnormalized.
__global__ __launch_bounds__(256, 4) void k_scores(
    const u16* __restrict__ Qb, const u16* __restrict__ Kpb,
    u16* __restrict__ Pb, float* __restrict__ rowsum)
{
  __shared__ __align__(16) u16 lds[16384];
  const int bx = blockIdx.x;
  const int b = bx / 136;
  const int tt = bx - b * 136;
  int bi = 0;
  while ((bi + 1) * (bi + 2) / 2 <= tt) ++bi;
  const int bj = tt - bi * (bi + 1) / 2;
  const int i0 = bi * 128, j0 = bj * 128;
  const u16* A = Qb + (size_t)b * 2048 * 1024;
  const u16* B = Kpb + (size_t)b * 2048 * 1024;

  f32x4 acc[4][4];
#pragma unroll
  for (int a = 0; a < 4; ++a)
#pragma unroll
    for (int c = 0; c < 4; ++c) acc[a][c] = (f32x4){0.f, 0.f, 0.f, 0.f};

  gemm128(A, 1024, B, 1024, i0, j0, 32, lds, acc);

  const int t = threadIdx.x, lane = t & 63, wid = t >> 6;
  const int wrow = wid >> 1, wcol = wid & 1;
  const int rr = lane & 15, kg = lane >> 4;
  float* lrs = (float*)lds;                    // reuse LDS: 128 row partials
  __syncthreads();
  if (t < 128) lrs[t] = 0.f;
  __syncthreads();
  u16* Pbb = Pb + (size_t)b * 2048 * 2048;
  const bool diag = (bi == bj);
#pragma unroll
  for (int mi = 0; mi < 4; ++mi)
#pragma unroll
    for (int r = 0; r < 4; ++r) {
      int lm = wrow * 64 + mi * 16 + kg * 4 + r;
      int m = i0 + lm;
      float rs = 0.f;
#pragma unroll
      for (int ni = 0; ni < 4; ++ni) {
        int n = j0 + wcol * 64 + ni * 16 + rr;
        float e = __expf(acc[mi][ni][r] * 0.03125f);
        if (diag && n > m) e = 0.f;
        Pbb[(size_t)m * 2048 + n] = f2b(e);
        rs += e;
      }
      rs += __shfl_xor(rs, 1, 16);             // reduce over the 16 rr lanes
      rs += __shfl_xor(rs, 2, 16);
      rs += __shfl_xor(rs, 4, 16);
      rs += __shfl_xor(rs, 8, 16);
      if (rr == 0) atomicAdd(&lrs[lm], rs);
    }
  __syncthreads();
  if (t < 128) atomicAdd(&rowsum[((size_t)b << 11) + i0 + t], lrs[t]);
}

// ---------- kernel 3: out = (Pexp @ V) / rowsum (pre-transposed Vtb) ------
// Depth-paired block mapping: u = bx>>5; bi = u<8 ? 15-u : u-8. CU c receives
// blocks c and c+256 -> depths (16-u)+(u+1) = 17 uniform across CUs.
__global__ __launch_bounds__(256, 4) void k_pv(
    const u16* __restrict__ Pb, const u16* __restrict__ Vtb,
    const float* __restrict__ rowsum, float* __restrict__ out)
{
  __shared__ __align__(16) u16 lds[16384];
  const int bx = blockIdx.x;
  const int bj = bx & 7;
  const int b = (bx >> 3) & 3;
  const int u = bx >> 5;
  const int bi = (u < 8) ? (15 - u) : (u - 8);
  const int i0 = bi * 128, j0 = bj * 128;
  const u16* A = Pb + (size_t)b * 2048 * 2048;   // lda 2048
  const u16* B = Vtb + (size_t)b * 1024 * 2048;  // ldb 2048

  f32x4 acc[4][4];
#pragma unroll
  for (int a = 0; a < 4; ++a)
#pragma unroll
    for (int c = 0; c < 4; ++c) acc[a][c] = (f32x4){0.f, 0.f, 0.f, 0.f};

  // causal: P zero for j >= (bi+1)*128 -> only (bi+1)*4 K-steps of 32
  gemm128(A, 2048, B, 2048, i0, j0, (bi + 1) * 4, lds, acc);

  const int t = threadIdx.x, lane = t & 63, wid = t >> 6;
  const int wrow = wid >> 1, wcol = wid & 1;
  const int rr = lane & 15, kg = lane >> 4;
  const float* rsb = rowsum + ((size_t)b << 11);
  float* ob = out + (size_t)b * 2048 * 1024;
#pragma unroll
  for (int mi = 0; mi < 4; ++mi)
#pragma unroll
    for (int r = 0; r < 4; ++r) {
      int m = i0 + wrow * 64 + mi * 16 + kg * 4 + r;
      float inv = 1.0f / rsb[m];
#pragma unroll
      for (int ni = 0; ni < 4; ++ni) {
        int n = j0 + wcol * 64 + ni * 16 + rr;
        ob[(size_t)m * 1024 + n] = acc[mi][ni][r] * inv;
      }
    }
}

// ---------- launch ----------
extern "C" void kernel_launch(void* const* d_in, const int* in_sizes, int n_in,
                              void* d_out, int out_size, void* d_ws, size_t ws_size,
                              hipStream_t stream) {
  const float* x  = (const float*)d_in[0];
  const float* Wq = (const float*)d_in[1];
  const float* bq = (const float*)d_in[2];
  const float* Wk = (const float*)d_in[3];
  const float* bk = (const float*)d_in[4];
  const float* Wv = (const float*)d_in[5];
  const float* bv = (const float*)d_in[6];
  const float* P  = (const float*)d_in[7];
  float* out = (float*)d_out;

  char* w = (char*)d_ws;
  u16*   xb     = (u16*)(w);                   // 16 MB
  u16*   Wb     = (u16*)(w + (16ull << 20));   //  6 MB
  u16*   Qb     = (u16*)(w + (22ull << 20));   // 16 MB
  u16*   Kpb    = (u16*)(w + (38ull << 20));   // 16 MB
  u16*   Vtb    = (u16*)(w + (54ull << 20));   // 16 MB
  u16*   Pb     = (u16*)(w + (70ull << 20));   // 32 MB
  u16*   Ptab   = (u16*)(w + (102ull << 20));  //  4 MB
  float* rowsum = (float*)(w + (106ull << 20));// 32 KB

  hipLaunchKernelGGL(k_convert, dim3(13313), dim3(256), 0, stream,
                     x, Wq, Wk, Wv, P, xb, Wb, Ptab, rowsum);
  hipLaunchKernelGGL(k_qkv, dim3(1536), dim3(256), 0, stream,
                     xb, Wb, bq, bk, bv, Ptab, Qb, Kpb, Vtb);
  hipLaunchKernelGGL(k_scores, dim3(544), dim3(256), 0, stream,
                     Qb, Kpb, Pb, rowsum);
  hipLaunchKernelGGL(k_pv, dim3(512), dim3(256), 0, stream,
                     Pb, Vtb, rowsum, out);
}